// Round 14
// baseline (124.782 us; speedup 1.0000x reference)
//
#include <hip/hip_runtime.h>
#include <hip/hip_bf16.h>
#include <math.h>

// MultiSimilarityLoss on MI355X.
// x: [n,128] fp32 L2-normalized; t: [n] int32 labels; out: 4 fp32
// (loss, prec, mean_pos_sim(last row), mean_neg_sim(last row)).
// ep = EPOCH_NUM/300 = 1.0, BASE=0.5, POS_MARGIN=0.9, NEG_MARGIN=0.1.
//
// R14: R13 (= R10, reproducible best 124.4us) with grid-tail fix:
// pos blocks FIRST (2048 of them, 16-way group split), neg tiles after —
// kernel tail becomes 2080 uniform neg tiles instead of high-variance
// pos blocks. Everything else byte-identical to R13.
// exp args expanded: neg 50(s-.5)+(.1-s)^2 = s^2+49.8s-24.99
//                    pos -2(s-.5)+(s-.9)^2 = s^2-3.8s+1.81

#define D 128
#define NL 128   // labels are 0..99; padded
#define POSB (NL * 16)   // pos sub-blocks: 16 per label group

typedef __attribute__((ext_vector_type(8))) short short8;
typedef __attribute__((ext_vector_type(4))) float float4v;

// ---------------- wave reduce helpers ----------------
__device__ inline float waveSum(float v) {
    #pragma unroll
    for (int o = 32; o > 0; o >>= 1) v += __shfl_down(v, o, 64);
    return v;
}
__device__ inline float waveMin(float v) {
    #pragma unroll
    for (int o = 32; o > 0; o >>= 1) v = fminf(v, __shfl_down(v, o, 64));
    return v;
}

// ---------------- kernel A: convert + bucket + zero workspace ---------------
__global__ __launch_bounds__(256) void prep_kernel(
    const float* __restrict__ x, ushort* __restrict__ xb, int total8,
    const int* __restrict__ t, int* __restrict__ offs, int* __restrict__ list,
    float* __restrict__ part, float* __restrict__ last4,
    float* __restrict__ out, int n, int nconv)
{
    const int tid = threadIdx.x;
    const int bx = blockIdx.x;
    if (bx < nconv) {
        const int g = bx * 256 + tid;
        if (g >= total8) return;
        const float4* src = (const float4*)(x) + g * 2;
        float4 a = src[0], b = src[1];
        float f[8] = {a.x, a.y, a.z, a.w, b.x, b.y, b.z, b.w};
        ushort r[8];
        #pragma unroll
        for (int i = 0; i < 8; ++i) {
            unsigned u = __float_as_uint(f[i]);
            r[i] = (ushort)((u + 0x7FFFu + ((u >> 16) & 1u)) >> 16);   // RNE
        }
        uint4 packed;
        packed.x = (unsigned)r[0] | ((unsigned)r[1] << 16);
        packed.y = (unsigned)r[2] | ((unsigned)r[3] << 16);
        packed.z = (unsigned)r[4] | ((unsigned)r[5] << 16);
        packed.w = (unsigned)r[6] | ((unsigned)r[7] << 16);
        ((uint4*)xb)[g] = packed;
        return;
    }
    if (bx > nconv) {   // zero part
        const int zb = bx - nconv - 1;
        const int g4 = zb * 1024 + tid * 4;
        if (g4 < 8 * n)
            *(float4*)(part + g4) = (float4){0.f, 0.f, 0.f, 0.f};
        return;
    }
    // bucketing block (also zeroes last4 and out accumulators)
    __shared__ int cnt[NL], cur[NL];
    if (tid < 4) { last4[tid] = 0.f; out[tid] = 0.f; }
    if (tid < NL) cnt[tid] = 0;
    __syncthreads();
    for (int j = tid; j < n; j += 256) atomicAdd(&cnt[t[j]], 1);
    __syncthreads();
    if (tid == 0) {
        int acc = 0;
        for (int g = 0; g < NL; ++g) { cur[g] = acc; offs[g] = acc; acc += cnt[g]; }
        offs[NL] = acc;
    }
    __syncthreads();
    for (int j = tid; j < n; j += 256) {
        int p = atomicAdd(&cur[t[j]], 1);
        list[p] = j;
    }
}

// ---------------- kernel B: FUSED pos stats + triangular MFMA neg ----------
// blocks [0,POSB): pos group sub-blocks. blocks [POSB,POSB+ntri): neg tiles.
__global__ __launch_bounds__(256, 3) void fused_kernel(
    const float* __restrict__ x, const ushort* __restrict__ xb,
    const int* __restrict__ t,
    const int* __restrict__ offs, const int* __restrict__ list,
    float* __restrict__ pos_min, float* __restrict__ pos_sum,
    float* __restrict__ part, float* __restrict__ last4, int n, int ntri)
{
    __shared__ __align__(16) unsigned char smem[32768 + 2048];
    const int tid = threadIdx.x;
    const int bx = blockIdx.x;

    if (bx >= POSB) {
        // ================= NEG tile path =================
        int b = bx - POSB;
        int r = (int)((sqrtf(8.0f * (float)b + 1.0f) - 1.0f) * 0.5f);
        while ((r + 1) * (r + 2) / 2 <= b) ++r;
        while (r * (r + 1) / 2 > b) --r;
        const int c = b - r * (r + 1) / 2;
        const bool offdiag = (r != c);

        const int w = tid >> 6, lane = tid & 63;
        const int wy = w >> 1, wx = w & 1;
        const int quad = lane >> 4, lq = lane & 15;
        const int i0 = r * 128, j0 = c * 128;
        const bool has_last = (i0 == n - 128);

        int* labr = (int*)(smem + 32768);
        int* labc = labr + 128;
        for (int l = tid; l < 128; l += 256) {
            labr[l] = t[i0 + l];
            labc[l] = t[j0 + l];
        }

        uint4* Au = (uint4*)smem;               // [128][8] chunks, swizzled
        uint4* Bu = Au + 128 * 8;
        const uint4* xbv = (const uint4*)xb;
        const short8* As = (const short8*)Au;
        const short8* Bs = (const short8*)Bu;

        float4v acc[4][4];
        #pragma unroll
        for (int a = 0; a < 4; ++a)
            #pragma unroll
            for (int d2 = 0; d2 < 4; ++d2) acc[a][d2] = (float4v){0.f, 0.f, 0.f, 0.f};

        #pragma unroll
        for (int h = 0; h < 2; ++h) {           // K half: cols [h*64, h*64+64)
            if (h) __syncthreads();             // done reading previous half
            #pragma unroll
            for (int it = 0; it < 4; ++it) {
                int gidx = tid + it * 256;      // 0..1023
                int row = gidx >> 3, q = gidx & 7;
                int qs = q ^ (row & 7);
                Au[row * 8 + qs] = xbv[(size_t)(i0 + row) * 16 + h * 8 + q];
                Bu[row * 8 + qs] = xbv[(size_t)(j0 + row) * 16 + h * 8 + q];
            }
            __syncthreads();
            #pragma unroll
            for (int s = 0; s < 2; ++s) {       // k = h*64 + s*32 + quad*8 + j
                short8 af[4], bf[4];
                #pragma unroll
                for (int tt = 0; tt < 4; ++tt) {
                    const int ra = wy * 64 + tt * 16 + lq;
                    const int rb2 = wx * 64 + tt * 16 + lq;
                    af[tt] = As[ra * 8 + ((s * 4 + quad) ^ (lq & 7))];
                    bf[tt] = Bs[rb2 * 8 + ((s * 4 + quad) ^ (lq & 7))];
                }
                #pragma unroll
                for (int tr = 0; tr < 4; ++tr)
                    #pragma unroll
                    for (int tc = 0; tc < 4; ++tc)
                        acc[tr][tc] = __builtin_amdgcn_mfma_f32_16x16x32_bf16(
                            af[tr], bf[tc], acc[tr][tc], 0, 0, 0);
            }
        }
        __syncthreads();     // all waves done reading A/B before aliasing

        float* pp_r = (float*)smem;             // [32][129] row partials
        float* pp_c = ((float*)smem) + 32 * 129;   // [8][129] col partials

        int lcv[4];
        #pragma unroll
        for (int tc = 0; tc < 4; ++tc) lcv[tc] = labc[wx * 64 + tc * 16 + lq];
        float colp[4] = {0.f, 0.f, 0.f, 0.f};

        #pragma unroll
        for (int tr = 0; tr < 4; ++tr) {
            #pragma unroll
            for (int reg = 0; reg < 4; ++reg) {
                const int row_loc = wy * 64 + tr * 16 + quad * 4 + reg;
                const int lr = labr[row_loc];
                float ns = 0.f;
                #pragma unroll
                for (int tc = 0; tc < 4; ++tc) {
                    const float s = acc[tr][tc][reg];
                    const bool sel = (lr != lcv[tc]) & (s > 0.1f);
                    const float e = sel
                        ? __expf(fmaf(s, s, fmaf(49.8f, s, -24.99f))) : 0.f;
                    ns += e; colp[tc] += e;
                }
                pp_r[(wx * 16 + lq) * 129 + row_loc] = ns;

                if (has_last && (i0 + row_loc == n - 1)) {  // last-row stats (pth=0.1)
                    float ssim = 0.f, ncf = 0.f;
                    #pragma unroll
                    for (int tc = 0; tc < 4; ++tc) {
                        const float s = acc[tr][tc][reg];
                        if ((lr != lcv[tc]) & (s > 0.1f)) { ssim += s; ncf += 1.f; }
                    }
                    #pragma unroll
                    for (int o = 1; o < 16; o <<= 1) {
                        ssim += __shfl_xor(ssim, o, 64);
                        ncf  += __shfl_xor(ncf, o, 64);
                    }
                    if (lq == 0 && ncf > 0.f) {
                        atomicAdd(&last4[2], ssim);
                        atomicAdd(&last4[3], ncf);
                    }
                }
            }
        }
        if (offdiag) {
            #pragma unroll
            for (int tc = 0; tc < 4; ++tc)
                pp_c[(wy * 4 + quad) * 129 + (wx * 64 + tc * 16 + lq)] = colp[tc];
        }
        __syncthreads();

        if (tid < 128) {
            float s = 0.f;
            #pragma unroll
            for (int cc = 0; cc < 32; ++cc) s += pp_r[cc * 129 + tid];
            atomicAdd(&part[(size_t)(c & 7) * n + i0 + tid], s);  // <=8 writers/slice
            if (offdiag) {
                float s2 = 0.f;
                #pragma unroll
                for (int cc = 0; cc < 8; ++cc) s2 += pp_c[cc * 129 + tid];
                atomicAdd(&part[(size_t)(r & 7) * n + j0 + tid], s2);
            }
        }
        return;
    }

    // ================= POS group path (16 sub-blocks per group) ============
    const int p = bx;
    const int g = p >> 4, sub = p & 15;
    const int s0 = offs[g], m = offs[g + 1] - s0;
    if (m <= 0) return;
    const int chunk = (m + 15) >> 4;
    const int rb = sub * chunk, re = min(m, rb + chunk);
    if (rb >= re) return;    // uniform per block, before any barrier

    uint4* cb = (uint4*)smem;                       // [128*16] swizzled cols
    float (*xi)[D] = (float(*)[D])(smem + 32768);   // [4][128] own rows fp32

    const int wid = tid >> 6, lane = tid & 63;
    const bool multi = (m > 128);

    if (!multi) {   // stage all group cols once
        for (int idx = tid; idx < m * 16; idx += 256) {
            int cl = idx >> 4, q = idx & 15;
            cb[cl * 16 + (q ^ (cl & 15))] =
                ((const uint4*)xb)[(size_t)list[s0 + cl] * 16 + q];
        }
        __syncthreads();
    }

    for (int r0 = rb; r0 < re; r0 += 4) {
        const int r = r0 + wid;
        const bool active = (r < re);
        const int i = active ? list[s0 + r] : 0;
        if (active && lane < 32)
            ((float4*)xi[wid])[lane] = ((const float4*)(x + (size_t)i * D))[lane];

        float mn = INFINITY, ps = 0.f, ss = 0.f, sc = 0.f;
        for (int c0 = 0; c0 < m; c0 += 128) {
            const int cc2 = min(128, m - c0);
            if (multi) {
                __syncthreads();
                for (int idx = tid; idx < cc2 * 16; idx += 256) {
                    int cl = idx >> 4, q = idx & 15;
                    cb[cl * 16 + (q ^ (cl & 15))] =
                        ((const uint4*)xb)[(size_t)list[s0 + c0 + cl] * 16 + q];
                }
                __syncthreads();
            }
            if (active) {
                const float* xu = xi[wid];
                for (int cl = lane; cl < cc2; cl += 64) {
                    float d = 0.f;
                    #pragma unroll
                    for (int q = 0; q < 16; ++q) {
                        uint4 v = cb[cl * 16 + (q ^ (cl & 15))];
                        const float* u = xu + q * 8;
                        d += __uint_as_float(v.x << 16)         * u[0];
                        d += __uint_as_float(v.x & 0xffff0000u) * u[1];
                        d += __uint_as_float(v.y << 16)         * u[2];
                        d += __uint_as_float(v.y & 0xffff0000u) * u[3];
                        d += __uint_as_float(v.z << 16)         * u[4];
                        d += __uint_as_float(v.z & 0xffff0000u) * u[5];
                        d += __uint_as_float(v.w << 16)         * u[6];
                        d += __uint_as_float(v.w & 0xffff0000u) * u[7];
                    }
                    if (d < 0.9f) {            // excludes j==i (sim ~ 1.0)
                        mn = fminf(mn, d);
                        ps += __expf(fmaf(d, d, fmaf(-3.8f, d, 1.81f)));
                        ss += d; sc += 1.f;
                    }
                }
            }
        }
        mn = waveMin(mn); ps = waveSum(ps); ss = waveSum(ss); sc = waveSum(sc);
        if (active && lane == 0) {
            pos_min[i] = mn;                   // mn>0.6 flags finalize recompute
            pos_sum[i] = ps;
            if (i == n - 1) { last4[0] = ss; last4[1] = sc; }
        }
    }
}

// ---------------- kernel C: finalize (32 blocks) + exact-path cleanup ------
__global__ __launch_bounds__(256) void finalize_kernel(
    const ushort* __restrict__ xb, const int* __restrict__ t,
    const float* __restrict__ pos_min, const float* __restrict__ pos_sum,
    const float* __restrict__ part, const float* __restrict__ last4,
    float* __restrict__ out, int n)
{
    const int tid = threadIdx.x;
    const int base = blockIdx.x * 256;
    const int i = base + tid;
    const float pm = pos_min[i];
    const bool flag = (pm > 0.6f);   // pth would exceed 0.1 (incl. pm=+inf)

    __shared__ int fl[256];
    __shared__ int nfl, lastflag;
    __shared__ float corr[256];
    __shared__ float xi2[D];
    __shared__ float red[3][4];
    __shared__ float lastst[2];
    if (tid == 0) { nfl = 0; lastflag = 0; }
    __syncthreads();
    if (flag) { int q = atomicAdd(&nfl, 1); fl[q] = tid; }
    __syncthreads();
    const int m = nfl;

    for (int e = 0; e < m; ++e) {    // rare: exact recompute of flagged rows
        const int lr_ = fl[e];
        const int ri = base + lr_;
        if (tid < D)
            xi2[tid] = __uint_as_float(((unsigned)xb[(size_t)ri * D + tid]) << 16);
        __syncthreads();
        const float pth = fmaxf(0.1f, pos_min[ri] - 0.5f);
        const int lab = t[ri];
        float S = 0.f, ss = 0.f, cnt = 0.f;
        for (int j = tid; j < n; j += 256) {
            if (t[j] == lab) continue;
            float d = 0.f;
            const ushort* xr = xb + (size_t)j * D;
            for (int q = 0; q < D; ++q)
                d += __uint_as_float(((unsigned)xr[q]) << 16) * xi2[q];
            if (d > pth) {
                S += __expf(fmaf(d, d, fmaf(49.8f, d, -24.99f)));
                ss += d; cnt += 1.f;
            }
        }
        const int lane = tid & 63, wv = tid >> 6;
        S = waveSum(S); ss = waveSum(ss); cnt = waveSum(cnt);
        if (lane == 0) { red[0][wv] = S; red[1][wv] = ss; red[2][wv] = cnt; }
        __syncthreads();
        if (tid == 0) {
            corr[lr_] = red[0][0] + red[0][1] + red[0][2] + red[0][3];
            if (ri == n - 1) {
                lastst[0] = red[1][0] + red[1][1] + red[1][2] + red[1][3];
                lastst[1] = red[2][0] + red[2][1] + red[2][2] + red[2][3];
                lastflag = 1;
            }
        }
        __syncthreads();
    }

    float s;
    if (flag) {
        s = corr[tid];
    } else {
        s = 0.f;
        #pragma unroll
        for (int sl = 0; sl < 8; ++sl) s += part[(size_t)sl * n + i];
    }
    float l = 0.f, nno = 0.f;
    if (s > 0.f)       // has_neg <=> any exp term (each > 0 in fp32)
        l = 0.5f * log1pf(pos_sum[i]) + 0.02f * log1pf(s);
    else
        nno = 1.f;
    const int lane = tid & 63, wv = tid >> 6;
    l = waveSum(l); nno = waveSum(nno);
    __syncthreads();                  // red[] reuse safety
    if (lane == 0) { red[0][wv] = l; red[1][wv] = nno; }
    __syncthreads();
    if (tid == 0) {
        float L = red[0][0] + red[0][1] + red[0][2] + red[0][3];
        float P = red[1][0] + red[1][1] + red[1][2] + red[1][3];
        atomicAdd(&out[0], L / (float)n);
        atomicAdd(&out[1], P / (float)n);
    }
    if (i == n - 1) {                 // block owning the last row writes stats
        out[2] = last4[0] / fmaxf(last4[1], 1.f);
        float a = lastflag ? lastst[0] : last4[2];
        float b2 = lastflag ? lastst[1] : last4[3];
        out[3] = a / fmaxf(b2, 1.f);
    }
}

// ---------------- launch ----------------
extern "C" void kernel_launch(void* const* d_in, const int* in_sizes, int n_in,
                              void* d_out, int out_size, void* d_ws, size_t ws_size,
                              hipStream_t stream) {
    const float* x = (const float*)d_in[0];
    const int*   t = (const int*)d_in[1];
    const int n = in_sizes[1];   // 8192

    float* ws      = (float*)d_ws;
    float* pos_min = ws;                       // [n]
    float* pos_sum = ws + n;                   // [n]
    float* last4   = ws + 2 * n;               // [4]   (zeroed by prep)
    float* part    = ws + 2 * n + 4;           // [8*n] (zeroed by prep)
    int*   offs    = (int*)(ws + 10 * n + 4);             // [NL+1]
    int*   list    = (int*)(ws + 10 * n + 4 + NL + 1);    // [n]
    size_t xb_off  = ((size_t)(11 * n + 4 + NL + 1) + 3) & ~(size_t)3;
    ushort* xb     = (ushort*)(ws + xb_off);              // [n*128] bf16, 16B aligned

    const int total8 = n * D / 8;
    const int nconv = (total8 + 255) / 256;
    const int nzero = (8 * n + 1023) / 1024;
    prep_kernel<<<nconv + 1 + nzero, 256, 0, stream>>>(
        x, xb, total8, t, offs, list, part, last4, (float*)d_out, n, nconv);

    const int nb = n / 128;                    // 64
    const int ntri = nb * (nb + 1) / 2;        // 2080
    fused_kernel<<<POSB + ntri, 256, 0, stream>>>(
        x, xb, t, offs, list, pos_min, pos_sum, part, last4, n, ntri);

    finalize_kernel<<<n / 256, 256, 0, stream>>>(xb, t, pos_min, pos_sum,
                                                 part, last4, (float*)d_out, n);
}

// Round 15
// 123.523 us; speedup vs baseline: 1.0102x; 1.0102x over previous
//
#include <hip/hip_runtime.h>
#include <hip/hip_bf16.h>
#include <math.h>

// MultiSimilarityLoss on MI355X.
// x: [n,128] fp32 L2-normalized; t: [n] int32 labels; out: 4 fp32
// (loss, prec, mean_pos_sim(last row), mean_neg_sim(last row)).
// ep = EPOCH_NUM/300 = 1.0, BASE=0.5, POS_MARGIN=0.9, NEG_MARGIN=0.1.
//
// R15: R14 + async global->LDS staging in the neg path via
// __builtin_amdgcn_global_load_lds(width=16). Swizzle moved to the
// GLOBAL side (lane fetches chunk qs^(row&7)) since the LDS dst is
// wave-uniform-base + lane*16 — final LDS layout identical, fragment
// reads stay conflict-free. Removes the VGPR round trip + ds_write pass
// per stage (m93->m97 evidence: width-16 lds-direct was the big ladder win).
// exp args expanded: neg 50(s-.5)+(.1-s)^2 = s^2+49.8s-24.99
//                    pos -2(s-.5)+(s-.9)^2 = s^2-3.8s+1.81

#define D 128
#define NL 128   // labels are 0..99; padded
#define POSB (NL * 16)   // pos sub-blocks: 16 per label group

typedef __attribute__((ext_vector_type(8))) short short8;
typedef __attribute__((ext_vector_type(4))) float float4v;

// ---------------- wave reduce helpers ----------------
__device__ inline float waveSum(float v) {
    #pragma unroll
    for (int o = 32; o > 0; o >>= 1) v += __shfl_down(v, o, 64);
    return v;
}
__device__ inline float waveMin(float v) {
    #pragma unroll
    for (int o = 32; o > 0; o >>= 1) v = fminf(v, __shfl_down(v, o, 64));
    return v;
}

// async 16B global->LDS (LDS dst: wave-uniform base + lane*16)
__device__ inline void load_lds16(const void* g, void* l) {
    __builtin_amdgcn_global_load_lds(
        (const __attribute__((address_space(1))) unsigned int*)g,
        (__attribute__((address_space(3))) unsigned int*)l, 16, 0, 0);
}

// ---------------- kernel A: convert + bucket + zero workspace ---------------
__global__ __launch_bounds__(256) void prep_kernel(
    const float* __restrict__ x, ushort* __restrict__ xb, int total8,
    const int* __restrict__ t, int* __restrict__ offs, int* __restrict__ list,
    float* __restrict__ part, float* __restrict__ last4,
    float* __restrict__ out, int n, int nconv)
{
    const int tid = threadIdx.x;
    const int bx = blockIdx.x;
    if (bx < nconv) {
        const int g = bx * 256 + tid;
        if (g >= total8) return;
        const float4* src = (const float4*)(x) + g * 2;
        float4 a = src[0], b = src[1];
        float f[8] = {a.x, a.y, a.z, a.w, b.x, b.y, b.z, b.w};
        ushort r[8];
        #pragma unroll
        for (int i = 0; i < 8; ++i) {
            unsigned u = __float_as_uint(f[i]);
            r[i] = (ushort)((u + 0x7FFFu + ((u >> 16) & 1u)) >> 16);   // RNE
        }
        uint4 packed;
        packed.x = (unsigned)r[0] | ((unsigned)r[1] << 16);
        packed.y = (unsigned)r[2] | ((unsigned)r[3] << 16);
        packed.z = (unsigned)r[4] | ((unsigned)r[5] << 16);
        packed.w = (unsigned)r[6] | ((unsigned)r[7] << 16);
        ((uint4*)xb)[g] = packed;
        return;
    }
    if (bx > nconv) {   // zero part
        const int zb = bx - nconv - 1;
        const int g4 = zb * 1024 + tid * 4;
        if (g4 < 8 * n)
            *(float4*)(part + g4) = (float4){0.f, 0.f, 0.f, 0.f};
        return;
    }
    // bucketing block (also zeroes last4 and out accumulators)
    __shared__ int cnt[NL], cur[NL];
    if (tid < 4) { last4[tid] = 0.f; out[tid] = 0.f; }
    if (tid < NL) cnt[tid] = 0;
    __syncthreads();
    for (int j = tid; j < n; j += 256) atomicAdd(&cnt[t[j]], 1);
    __syncthreads();
    if (tid == 0) {
        int acc = 0;
        for (int g = 0; g < NL; ++g) { cur[g] = acc; offs[g] = acc; acc += cnt[g]; }
        offs[NL] = acc;
    }
    __syncthreads();
    for (int j = tid; j < n; j += 256) {
        int p = atomicAdd(&cur[t[j]], 1);
        list[p] = j;
    }
}

// ---------------- kernel B: FUSED pos stats + triangular MFMA neg ----------
// blocks [0,POSB): pos group sub-blocks. blocks [POSB,POSB+ntri): neg tiles.
__global__ __launch_bounds__(256, 3) void fused_kernel(
    const float* __restrict__ x, const ushort* __restrict__ xb,
    const int* __restrict__ t,
    const int* __restrict__ offs, const int* __restrict__ list,
    float* __restrict__ pos_min, float* __restrict__ pos_sum,
    float* __restrict__ part, float* __restrict__ last4, int n, int ntri)
{
    __shared__ __align__(16) unsigned char smem[32768 + 2048];
    const int tid = threadIdx.x;
    const int bx = blockIdx.x;

    if (bx >= POSB) {
        // ================= NEG tile path =================
        int b = bx - POSB;
        int r = (int)((sqrtf(8.0f * (float)b + 1.0f) - 1.0f) * 0.5f);
        while ((r + 1) * (r + 2) / 2 <= b) ++r;
        while (r * (r + 1) / 2 > b) --r;
        const int c = b - r * (r + 1) / 2;
        const bool offdiag = (r != c);

        const int w = tid >> 6, lane = tid & 63;
        const int wy = w >> 1, wx = w & 1;
        const int quad = lane >> 4, lq = lane & 15;
        const int i0 = r * 128, j0 = c * 128;
        const bool has_last = (i0 == n - 128);

        int* labr = (int*)(smem + 32768);
        int* labc = labr + 128;
        for (int l = tid; l < 128; l += 256) {
            labr[l] = t[i0 + l];
            labc[l] = t[j0 + l];
        }

        uint4* Au = (uint4*)smem;               // [128][8] chunks, swizzled
        uint4* Bu = Au + 128 * 8;
        const uint4* xbv = (const uint4*)xb;
        const short8* As = (const short8*)Au;
        const short8* Bs = (const short8*)Bu;

        float4v acc[4][4];
        #pragma unroll
        for (int a = 0; a < 4; ++a)
            #pragma unroll
            for (int d2 = 0; d2 < 4; ++d2) acc[a][d2] = (float4v){0.f, 0.f, 0.f, 0.f};

        #pragma unroll
        for (int h = 0; h < 2; ++h) {           // K half: cols [h*64, h*64+64)
            if (h) __syncthreads();             // done reading previous half
            // async stage: dst slot d = tid + it*256; LDS dst is uniform
            // base (it*256 + wave*64)*16 + lane*16; swizzle on global side.
            #pragma unroll
            for (int it = 0; it < 4; ++it) {
                const int d = tid + it * 256;   // 0..1023
                const int row = d >> 3;
                const int q = (d & 7) ^ (row & 7);
                const int ub = (d & ~63) * 16;  // wave-uniform byte offset
                load_lds16(xbv + (size_t)(i0 + row) * 16 + h * 8 + q,
                           (char*)Au + ub);
                load_lds16(xbv + (size_t)(j0 + row) * 16 + h * 8 + q,
                           (char*)Bu + ub);
            }
            __syncthreads();                    // drains vmcnt (loads landed)
            #pragma unroll
            for (int s = 0; s < 2; ++s) {       // k = h*64 + s*32 + quad*8 + j
                short8 af[4], bf[4];
                #pragma unroll
                for (int tt = 0; tt < 4; ++tt) {
                    const int ra = wy * 64 + tt * 16 + lq;
                    const int rb2 = wx * 64 + tt * 16 + lq;
                    af[tt] = As[ra * 8 + ((s * 4 + quad) ^ (lq & 7))];
                    bf[tt] = Bs[rb2 * 8 + ((s * 4 + quad) ^ (lq & 7))];
                }
                #pragma unroll
                for (int tr = 0; tr < 4; ++tr)
                    #pragma unroll
                    for (int tc = 0; tc < 4; ++tc)
                        acc[tr][tc] = __builtin_amdgcn_mfma_f32_16x16x32_bf16(
                            af[tr], bf[tc], acc[tr][tc], 0, 0, 0);
            }
        }
        __syncthreads();     // all waves done reading A/B before aliasing

        float* pp_r = (float*)smem;             // [32][129] row partials
        float* pp_c = ((float*)smem) + 32 * 129;   // [8][129] col partials

        int lcv[4];
        #pragma unroll
        for (int tc = 0; tc < 4; ++tc) lcv[tc] = labc[wx * 64 + tc * 16 + lq];
        float colp[4] = {0.f, 0.f, 0.f, 0.f};

        #pragma unroll
        for (int tr = 0; tr < 4; ++tr) {
            #pragma unroll
            for (int reg = 0; reg < 4; ++reg) {
                const int row_loc = wy * 64 + tr * 16 + quad * 4 + reg;
                const int lr = labr[row_loc];
                float ns = 0.f;
                #pragma unroll
                for (int tc = 0; tc < 4; ++tc) {
                    const float s = acc[tr][tc][reg];
                    const bool sel = (lr != lcv[tc]) & (s > 0.1f);
                    const float e = sel
                        ? __expf(fmaf(s, s, fmaf(49.8f, s, -24.99f))) : 0.f;
                    ns += e; colp[tc] += e;
                }
                pp_r[(wx * 16 + lq) * 129 + row_loc] = ns;

                if (has_last && (i0 + row_loc == n - 1)) {  // last-row stats (pth=0.1)
                    float ssim = 0.f, ncf = 0.f;
                    #pragma unroll
                    for (int tc = 0; tc < 4; ++tc) {
                        const float s = acc[tr][tc][reg];
                        if ((lr != lcv[tc]) & (s > 0.1f)) { ssim += s; ncf += 1.f; }
                    }
                    #pragma unroll
                    for (int o = 1; o < 16; o <<= 1) {
                        ssim += __shfl_xor(ssim, o, 64);
                        ncf  += __shfl_xor(ncf, o, 64);
                    }
                    if (lq == 0 && ncf > 0.f) {
                        atomicAdd(&last4[2], ssim);
                        atomicAdd(&last4[3], ncf);
                    }
                }
            }
        }
        if (offdiag) {
            #pragma unroll
            for (int tc = 0; tc < 4; ++tc)
                pp_c[(wy * 4 + quad) * 129 + (wx * 64 + tc * 16 + lq)] = colp[tc];
        }
        __syncthreads();

        if (tid < 128) {
            float s = 0.f;
            #pragma unroll
            for (int cc = 0; cc < 32; ++cc) s += pp_r[cc * 129 + tid];
            atomicAdd(&part[(size_t)(c & 7) * n + i0 + tid], s);  // <=8 writers/slice
            if (offdiag) {
                float s2 = 0.f;
                #pragma unroll
                for (int cc = 0; cc < 8; ++cc) s2 += pp_c[cc * 129 + tid];
                atomicAdd(&part[(size_t)(r & 7) * n + j0 + tid], s2);
            }
        }
        return;
    }

    // ================= POS group path (16 sub-blocks per group) ============
    const int p = bx;
    const int g = p >> 4, sub = p & 15;
    const int s0 = offs[g], m = offs[g + 1] - s0;
    if (m <= 0) return;
    const int chunk = (m + 15) >> 4;
    const int rb = sub * chunk, re = min(m, rb + chunk);
    if (rb >= re) return;    // uniform per block, before any barrier

    uint4* cb = (uint4*)smem;                       // [128*16] swizzled cols
    float (*xi)[D] = (float(*)[D])(smem + 32768);   // [4][128] own rows fp32

    const int wid = tid >> 6, lane = tid & 63;
    const bool multi = (m > 128);

    if (!multi) {   // stage all group cols once
        for (int idx = tid; idx < m * 16; idx += 256) {
            int cl = idx >> 4, q = idx & 15;
            cb[cl * 16 + (q ^ (cl & 15))] =
                ((const uint4*)xb)[(size_t)list[s0 + cl] * 16 + q];
        }
        __syncthreads();
    }

    for (int r0 = rb; r0 < re; r0 += 4) {
        const int r = r0 + wid;
        const bool active = (r < re);
        const int i = active ? list[s0 + r] : 0;
        if (active && lane < 32)
            ((float4*)xi[wid])[lane] = ((const float4*)(x + (size_t)i * D))[lane];

        float mn = INFINITY, ps = 0.f, ss = 0.f, sc = 0.f;
        for (int c0 = 0; c0 < m; c0 += 128) {
            const int cc2 = min(128, m - c0);
            if (multi) {
                __syncthreads();
                for (int idx = tid; idx < cc2 * 16; idx += 256) {
                    int cl = idx >> 4, q = idx & 15;
                    cb[cl * 16 + (q ^ (cl & 15))] =
                        ((const uint4*)xb)[(size_t)list[s0 + c0 + cl] * 16 + q];
                }
                __syncthreads();
            }
            if (active) {
                const float* xu = xi[wid];
                for (int cl = lane; cl < cc2; cl += 64) {
                    float d = 0.f;
                    #pragma unroll
                    for (int q = 0; q < 16; ++q) {
                        uint4 v = cb[cl * 16 + (q ^ (cl & 15))];
                        const float* u = xu + q * 8;
                        d += __uint_as_float(v.x << 16)         * u[0];
                        d += __uint_as_float(v.x & 0xffff0000u) * u[1];
                        d += __uint_as_float(v.y << 16)         * u[2];
                        d += __uint_as_float(v.y & 0xffff0000u) * u[3];
                        d += __uint_as_float(v.z << 16)         * u[4];
                        d += __uint_as_float(v.z & 0xffff0000u) * u[5];
                        d += __uint_as_float(v.w << 16)         * u[6];
                        d += __uint_as_float(v.w & 0xffff0000u) * u[7];
                    }
                    if (d < 0.9f) {            // excludes j==i (sim ~ 1.0)
                        mn = fminf(mn, d);
                        ps += __expf(fmaf(d, d, fmaf(-3.8f, d, 1.81f)));
                        ss += d; sc += 1.f;
                    }
                }
            }
        }
        mn = waveMin(mn); ps = waveSum(ps); ss = waveSum(ss); sc = waveSum(sc);
        if (active && lane == 0) {
            pos_min[i] = mn;                   // mn>0.6 flags finalize recompute
            pos_sum[i] = ps;
            if (i == n - 1) { last4[0] = ss; last4[1] = sc; }
        }
    }
}

// ---------------- kernel C: finalize (32 blocks) + exact-path cleanup ------
__global__ __launch_bounds__(256) void finalize_kernel(
    const ushort* __restrict__ xb, const int* __restrict__ t,
    const float* __restrict__ pos_min, const float* __restrict__ pos_sum,
    const float* __restrict__ part, const float* __restrict__ last4,
    float* __restrict__ out, int n)
{
    const int tid = threadIdx.x;
    const int base = blockIdx.x * 256;
    const int i = base + tid;
    const float pm = pos_min[i];
    const bool flag = (pm > 0.6f);   // pth would exceed 0.1 (incl. pm=+inf)

    __shared__ int fl[256];
    __shared__ int nfl, lastflag;
    __shared__ float corr[256];
    __shared__ float xi2[D];
    __shared__ float red[3][4];
    __shared__ float lastst[2];
    if (tid == 0) { nfl = 0; lastflag = 0; }
    __syncthreads();
    if (flag) { int q = atomicAdd(&nfl, 1); fl[q] = tid; }
    __syncthreads();
    const int m = nfl;

    for (int e = 0; e < m; ++e) {    // rare: exact recompute of flagged rows
        const int lr_ = fl[e];
        const int ri = base + lr_;
        if (tid < D)
            xi2[tid] = __uint_as_float(((unsigned)xb[(size_t)ri * D + tid]) << 16);
        __syncthreads();
        const float pth = fmaxf(0.1f, pos_min[ri] - 0.5f);
        const int lab = t[ri];
        float S = 0.f, ss = 0.f, cnt = 0.f;
        for (int j = tid; j < n; j += 256) {
            if (t[j] == lab) continue;
            float d = 0.f;
            const ushort* xr = xb + (size_t)j * D;
            for (int q = 0; q < D; ++q)
                d += __uint_as_float(((unsigned)xr[q]) << 16) * xi2[q];
            if (d > pth) {
                S += __expf(fmaf(d, d, fmaf(49.8f, d, -24.99f)));
                ss += d; cnt += 1.f;
            }
        }
        const int lane = tid & 63, wv = tid >> 6;
        S = waveSum(S); ss = waveSum(ss); cnt = waveSum(cnt);
        if (lane == 0) { red[0][wv] = S; red[1][wv] = ss; red[2][wv] = cnt; }
        __syncthreads();
        if (tid == 0) {
            corr[lr_] = red[0][0] + red[0][1] + red[0][2] + red[0][3];
            if (ri == n - 1) {
                lastst[0] = red[1][0] + red[1][1] + red[1][2] + red[1][3];
                lastst[1] = red[2][0] + red[2][1] + red[2][2] + red[2][3];
                lastflag = 1;
            }
        }
        __syncthreads();
    }

    float s;
    if (flag) {
        s = corr[tid];
    } else {
        s = 0.f;
        #pragma unroll
        for (int sl = 0; sl < 8; ++sl) s += part[(size_t)sl * n + i];
    }
    float l = 0.f, nno = 0.f;
    if (s > 0.f)       // has_neg <=> any exp term (each > 0 in fp32)
        l = 0.5f * log1pf(pos_sum[i]) + 0.02f * log1pf(s);
    else
        nno = 1.f;
    const int lane = tid & 63, wv = tid >> 6;
    l = waveSum(l); nno = waveSum(nno);
    __syncthreads();                  // red[] reuse safety
    if (lane == 0) { red[0][wv] = l; red[1][wv] = nno; }
    __syncthreads();
    if (tid == 0) {
        float L = red[0][0] + red[0][1] + red[0][2] + red[0][3];
        float P = red[1][0] + red[1][1] + red[1][2] + red[1][3];
        atomicAdd(&out[0], L / (float)n);
        atomicAdd(&out[1], P / (float)n);
    }
    if (i == n - 1) {                 // block owning the last row writes stats
        out[2] = last4[0] / fmaxf(last4[1], 1.f);
        float a = lastflag ? lastst[0] : last4[2];
        float b2 = lastflag ? lastst[1] : last4[3];
        out[3] = a / fmaxf(b2, 1.f);
    }
}

// ---------------- launch ----------------
extern "C" void kernel_launch(void* const* d_in, const int* in_sizes, int n_in,
                              void* d_out, int out_size, void* d_ws, size_t ws_size,
                              hipStream_t stream) {
    const float* x = (const float*)d_in[0];
    const int*   t = (const int*)d_in[1];
    const int n = in_sizes[1];   // 8192

    float* ws      = (float*)d_ws;
    float* pos_min = ws;                       // [n]
    float* pos_sum = ws + n;                   // [n]
    float* last4   = ws + 2 * n;               // [4]   (zeroed by prep)
    float* part    = ws + 2 * n + 4;           // [8*n] (zeroed by prep)
    int*   offs    = (int*)(ws + 10 * n + 4);             // [NL+1]
    int*   list    = (int*)(ws + 10 * n + 4 + NL + 1);    // [n]
    size_t xb_off  = ((size_t)(11 * n + 4 + NL + 1) + 3) & ~(size_t)3;
    ushort* xb     = (ushort*)(ws + xb_off);              // [n*128] bf16, 16B aligned

    const int total8 = n * D / 8;
    const int nconv = (total8 + 255) / 256;
    const int nzero = (8 * n + 1023) / 1024;
    prep_kernel<<<nconv + 1 + nzero, 256, 0, stream>>>(
        x, xb, total8, t, offs, list, part, last4, (float*)d_out, n, nconv);

    const int nb = n / 128;                    // 64
    const int ntri = nb * (nb + 1) / 2;        // 2080
    fused_kernel<<<POSB + ntri, 256, 0, stream>>>(
        x, xb, t, offs, list, pos_min, pos_sum, part, last4, n, ntri);

    finalize_kernel<<<n / 256, 256, 0, stream>>>(xb, t, pos_min, pos_sum,
                                                 part, last4, (float*)d_out, n);
}